// Round 5
// baseline (247.164 us; speedup 1.0000x reference)
//
#include <hip/hip_runtime.h>

// B = 16777216 rows, 2 cols. 2048 blocks x 8192 elems, 32 elems/thread.
#define E_BLOCK 8192
#define E_WAVE  2048
#define QITERS  8              // per-thread iterations, 4 consecutive elems each

#define M1f     0.2771814156f  // 0.5*(85/900)^0.25  (class-1 LDAM margin)
#define C_A1    60.0f          // za = tf*60 - 30      -> +-30
#define C_C1    (30.0f*M1f - 15.0f) // zc = tf*C_C1 + 15

#define EXP2F(v) __builtin_amdgcn_exp2f(v)   // v_exp_f32: 2^x
#define LOG2F(v) __builtin_amdgcn_logf(v)    // v_log_f32: log2(x)

struct BlockRec {
  int s0, p0, s1, p1;   // chain sum + packed (f+1) | (l+1)<<4 per class
  float wnll, fl;
  int cnt1, pad;
};

// 0-encoded chain state: f==0 => empty. f,l in {-1,0,+1}. Ordered combine.
__device__ __forceinline__ void comb0(int &s, int &f, int &l, int sb, int fb, int lb) {
  s += sb + l * fb;
  f = f ? f : fb;
  l = fb ? lb : l;
}

__device__ __forceinline__ void bfly_step(int m, int lane, int &s, int &f, int &l) {
  const int os = __shfl_xor(s, m), of = __shfl_xor(f, m), ol = __shfl_xor(l, m);
  const bool up = (lane & m) != 0;
  int as = up ? os : s, af = up ? of : f, al = up ? ol : l;
  const int bs = up ? s : os, bf = up ? f : of, bl = up ? l : ol;
  comb0(as, af, al, bs, bf, bl);
  s = as; f = af; l = al;
}

__device__ __forceinline__ void elem_math(float x0, float x1, int t, int k,
                                          float &wnll, float &flraw, int &cnt1,
                                          unsigned int &word) {
  const float tf  = (float)t;
  const float wgt = fmaf(tf, 0.7f, 0.15f);          // 0.15 / 0.85
  const float d   = x0 - x1;
  const float za  = fmaf(tf, C_A1, -30.0f);
  const float zc  = fmaf(tf, C_C1, 15.0f);
  const float z   = fmaf(za, d, zc);                // 30*(t? d+M1 : 0.5-d)
  const float ex  = EXP2F(fabsf(z) * -1.44269504f);
  const float lp  = LOG2F(1.0f + ex);
  const float sp  = fmaf(0.69314718f, lp, fmaxf(z, 0.0f));  // softplus(z)
  wnll = fmaf(wgt, sp, wnll);
  const float om  = 1.0f - x1;
  const float q   = t ? x1 : om;
  const float r   = t ? om : x1;
  const float lg2 = LOG2F(q + 1e-9f);
  const float wr2 = (wgt * r) * r;
  flraw = fmaf(wr2, lg2, flraw);                    // * -ln2 applied at end
  cnt1 += t;
  const unsigned int code = 4u | (unsigned int)(d > 0.0f) | ((unsigned int)t << 1);
  word |= code << (8 * k);
}

__global__ __launch_bounds__(256, 8) void loss_pass1(
    const float* __restrict__ x, const int* __restrict__ tgt,
    BlockRec* __restrict__ recs, int B) {
  // LDS words: [0,2304) chunk words (thread t owns 9t..9t+7, stride-9 pad);
  // [2304,2560) packed states; [2560,2816) wnll; [2816,3072) fls; [3072,3328) cnt.
  __shared__ unsigned int lds[3328];
  unsigned int* chunkw = lds;
  unsigned int* stw = lds + 2304;
  float* wnw = (float*)(lds + 2560);
  float* flw = (float*)(lds + 2816);
  int*   cnw = (int*)(lds + 3072);

  const int tid = threadIdx.x;
  const int w = tid >> 6, lane = tid & 63;
  const int waveBase = blockIdx.x * E_BLOCK + w * E_WAVE;

  float wnll = 0.f, flraw = 0.f; int cnt1 = 0;

  if (waveBase + E_WAVE <= B) {
    // fast path: wave fully in range
    const int e0 = waveBase + lane * 4;
    const float4* __restrict__ px = (const float4*)(x + 2 * (size_t)e0);
    const int4*   __restrict__ pt = (const int4*)(tgt + e0);

    float4 xa = px[0], xb = px[1];
    int4  t4 = pt[0];
    for (int j = 0; j < QITERS; ++j) {
      float4 xa_n, xb_n; int4 t4_n;
      if (j + 1 < QITERS) {                 // prefetch next iteration (3 loads in flight)
        const int o = (j + 1) * 128;
        xa_n = px[o]; xb_n = px[o + 1]; t4_n = pt[(j + 1) * 64];
      }
      unsigned int word = 0;
      elem_math(xa.x, xa.y, t4.x, 0, wnll, flraw, cnt1, word);
      elem_math(xa.z, xa.w, t4.y, 1, wnll, flraw, cnt1, word);
      elem_math(xb.x, xb.y, t4.z, 2, wnll, flraw, cnt1, word);
      elem_math(xb.z, xb.w, t4.w, 3, wnll, flraw, cnt1, word);
      const int qi = w * 512 + (j << 6) + lane;        // block-local quad index
      chunkw[(qi >> 3) * 9 + (qi & 7)] = word;
      xa = xa_n; xb = xb_n; t4 = t4_n;
    }
  } else {
    // slow path: per-element guard (only the final partial block, if any)
    for (int j = 0; j < QITERS; ++j) {
      unsigned int word = 0;
      for (int k = 0; k < 4; ++k) {
        const int e = waveBase + ((j << 6) + lane) * 4 + k;
        if (e < B) {
          elem_math(x[2 * (size_t)e], x[2 * (size_t)e + 1], tgt[e], k,
                    wnll, flraw, cnt1, word);
        }
      }
      const int qi = w * 512 + (j << 6) + lane;
      chunkw[(qi >> 3) * 9 + (qi & 7)] = word;
    }
  }
  __syncthreads();

  // Phase 2: each thread serially chains its contiguous 32-element chunk.
  int s0 = 0, f0 = 0, l0 = 0, s1 = 0, f1 = 0, l1 = 0;
  #pragma unroll
  for (int r = 0; r < 8; ++r) {
    const unsigned int wv = chunkw[tid * 9 + r];
    #pragma unroll
    for (int k = 0; k < 4; ++k) {
      const unsigned int b = (wv >> (8 * k)) & 7u;
      if (b & 4u) {
        const int sv = (int)((b & 1u) << 1) - 1;
        const int t  = (int)((b >> 1) & 1u);
        const int lv = t ? l1 : l0;
        const int add = lv * sv;
        if (t) { s1 += add; l1 = sv; f1 = f1 ? f1 : sv; }
        else   { s0 += add; l0 = sv; f0 = f0 ? f0 : sv; }
      }
    }
  }
  stw[tid] = (unsigned)(s0 + 128) | ((unsigned)(f0 + 1) << 8) | ((unsigned)(l0 + 1) << 10)
           | ((unsigned)(s1 + 128) << 16) | ((unsigned)(f1 + 1) << 24) | ((unsigned)(l1 + 1) << 26);
  wnw[tid] = wnll; flw[tid] = flraw * -0.69314718f; cnw[tid] = cnt1;
  __syncthreads();

  if (w == 0) {
    int S0 = 0, F0 = 0, L0 = 0, S1 = 0, F1 = 0, L1 = 0;
    float W = 0.f, F = 0.f; int C = 0;
    #pragma unroll
    for (int q = 0; q < 4; ++q) {
      const int i = lane * 4 + q;                 // ascending element order
      const unsigned int pk = stw[i];
      comb0(S0, F0, L0, (int)(pk & 255u) - 128, (int)((pk >> 8) & 3u) - 1, (int)((pk >> 10) & 3u) - 1);
      comb0(S1, F1, L1, (int)((pk >> 16) & 255u) - 128, (int)((pk >> 24) & 3u) - 1, (int)((pk >> 26) & 3u) - 1);
      W += wnw[i]; F += flw[i]; C += cnw[i];
    }
    #pragma unroll
    for (int k = 0; k < 6; ++k) {
      const int m = 1 << k;
      bfly_step(m, lane, S0, F0, L0);
      bfly_step(m, lane, S1, F1, L1);
      W += __shfl_xor(W, m); F += __shfl_xor(F, m); C += __shfl_xor(C, m);
    }
    if (lane == 0) {
      BlockRec r;
      r.s0 = S0; r.p0 = (F0 + 1) | ((L0 + 1) << 4);
      r.s1 = S1; r.p1 = (F1 + 1) | ((L1 + 1) << 4);
      r.wnll = W; r.fl = F; r.cnt1 = C; r.pad = 0;
      recs[blockIdx.x] = r;
    }
  }
}

__global__ __launch_bounds__(256) void loss_pass2(
    const BlockRec* __restrict__ recs, int NB, int B, float* __restrict__ out) {
  __shared__ int sS0[256], sF0[256], sL0[256], sS1[256], sF1[256], sL1[256], sC[256];
  __shared__ double sW[256], sFl[256];
  const int tid = threadIdx.x, w = tid >> 6, lane = tid & 63;
  const int R = (NB + 255) >> 8;

  int s0 = 0, f0 = 0, l0 = 0, s1 = 0, f1 = 0, l1 = 0;
  double W = 0.0, Fd = 0.0; int C = 0;
  for (int r = 0; r < R; ++r) {
    const int b = tid * R + r;
    if (b < NB) {
      const BlockRec rec = recs[b];
      comb0(s0, f0, l0, rec.s0, (rec.p0 & 3) - 1, ((rec.p0 >> 4) & 3) - 1);
      comb0(s1, f1, l1, rec.s1, (rec.p1 & 3) - 1, ((rec.p1 >> 4) & 3) - 1);
      W += (double)rec.wnll; Fd += (double)rec.fl; C += rec.cnt1;
    }
  }
  sS0[tid] = s0; sF0[tid] = f0; sL0[tid] = l0;
  sS1[tid] = s1; sF1[tid] = f1; sL1[tid] = l1;
  sC[tid] = C; sW[tid] = W; sFl[tid] = Fd;
  __syncthreads();

  if (w == 0) {
    int S0 = 0, F0 = 0, L0 = 0, S1 = 0, F1 = 0, L1 = 0; int Ct = 0;
    double Wt = 0.0, Ft = 0.0;
    #pragma unroll
    for (int q = 0; q < 4; ++q) {
      const int i = lane * 4 + q;
      comb0(S0, F0, L0, sS0[i], sF0[i], sL0[i]);
      comb0(S1, F1, L1, sS1[i], sF1[i], sL1[i]);
      Wt += sW[i]; Ft += sFl[i]; Ct += sC[i];
    }
    #pragma unroll
    for (int k = 0; k < 6; ++k) {
      const int m = 1 << k;
      bfly_step(m, lane, S0, F0, L0);
      bfly_step(m, lane, S1, F1, L1);
      Wt += __shfl_xor(Wt, m); Ft += __shfl_xor(Ft, m); Ct += __shfl_xor(Ct, m);
    }
    if (lane == 0) {
      const double n1 = (double)Ct, n0 = (double)B - n1;
      const double sw = 0.15 * n0 + 0.85 * n1;
      const double ldam  = Wt / sw;
      const double focal = Ft / (double)B;
      const double q0 = (n0 > 0.0) ? (double)S0 / n0 : 0.0;
      const double q1 = (n1 > 0.0) ? (double)S1 / n1 : 0.0;
      const double dq = q0 - q1;
      out[0] = (float)(ldam + focal + dq * dq);
    }
  }
}

extern "C" void kernel_launch(void* const* d_in, const int* in_sizes, int n_in,
                              void* d_out, int out_size, void* d_ws, size_t ws_size,
                              hipStream_t stream) {
  const float* x  = (const float*)d_in[0];
  const int* tgt  = (const int*)d_in[1];
  float* out      = (float*)d_out;
  const int B  = in_sizes[1];                       // rows (16777216)
  const int NB = (B + E_BLOCK - 1) / E_BLOCK;       // 2048
  BlockRec* recs = (BlockRec*)d_ws;                 // 64 KB scratch
  loss_pass1<<<NB, 256, 0, stream>>>(x, tgt, recs, B);
  loss_pass2<<<1, 256, 0, stream>>>(recs, NB, B, out);
}

// Round 6
// 242.396 us; speedup vs baseline: 1.0197x; 1.0197x over previous
//
#include <hip/hip_runtime.h>

// B = 16777216 rows, 2 cols. 2048 blocks x 8192 elems, 32 elems/thread.
#define E_BLOCK 8192
#define E_WAVE  2048
#define QITERS  8              // per-thread iterations, 4 consecutive elems each
#define PF      2              // prefetch depth (iterations ahead, in registers)

#define M1f     0.2771814156f  // 0.5*(85/900)^0.25  (class-1 LDAM margin)
#define C_A1    60.0f          // za = tf*60 - 30      -> +-30
#define C_C1    (30.0f*M1f - 15.0f) // zc = tf*C_C1 + 15

#define EXP2F(v) __builtin_amdgcn_exp2f(v)   // v_exp_f32: 2^x
#define LOG2F(v) __builtin_amdgcn_logf(v)    // v_log_f32: log2(x)

struct BlockRec {
  int s0, p0, s1, p1;   // chain sum + packed (f+1) | (l+1)<<4 per class
  float wnll, fl;
  int cnt1, pad;
};

// 0-encoded chain state: f==0 => empty. f,l in {-1,0,+1}. Ordered combine.
__device__ __forceinline__ void comb0(int &s, int &f, int &l, int sb, int fb, int lb) {
  s += sb + l * fb;
  f = f ? f : fb;
  l = fb ? lb : l;
}

__device__ __forceinline__ void bfly_step(int m, int lane, int &s, int &f, int &l) {
  const int os = __shfl_xor(s, m), of = __shfl_xor(f, m), ol = __shfl_xor(l, m);
  const bool up = (lane & m) != 0;
  int as = up ? os : s, af = up ? of : f, al = up ? ol : l;
  const int bs = up ? s : os, bf = up ? f : of, bl = up ? l : ol;
  comb0(as, af, al, bs, bf, bl);
  s = as; f = af; l = al;
}

__device__ __forceinline__ void elem_math(float x0, float x1, int t, int k,
                                          float &wnll, float &flraw, int &cnt1,
                                          unsigned int &word) {
  const float tf  = (float)t;
  const float wgt = fmaf(tf, 0.7f, 0.15f);          // 0.15 / 0.85
  const float d   = x0 - x1;
  const float za  = fmaf(tf, C_A1, -30.0f);
  const float zc  = fmaf(tf, C_C1, 15.0f);
  const float z   = fmaf(za, d, zc);                // 30*(t? d+M1 : 0.5-d)
  const float ex  = EXP2F(fabsf(z) * -1.44269504f);
  const float lp  = LOG2F(1.0f + ex);
  const float sp  = fmaf(0.69314718f, lp, fmaxf(z, 0.0f));  // softplus(z)
  wnll = fmaf(wgt, sp, wnll);
  const float om  = 1.0f - x1;
  const float q   = t ? x1 : om;
  const float r   = t ? om : x1;
  const float lg2 = LOG2F(q + 1e-9f);
  const float wr2 = (wgt * r) * r;
  flraw = fmaf(wr2, lg2, flraw);                    // * -ln2 applied at end
  cnt1 += t;
  const unsigned int code = 4u | (unsigned int)(d > 0.0f) | ((unsigned int)t << 1);
  word |= code << (8 * k);
}

__global__ __launch_bounds__(256, 4) void loss_pass1(
    const float* __restrict__ x, const int* __restrict__ tgt,
    BlockRec* __restrict__ recs, int B) {
  // LDS words: [0,2304) chunk words (thread t owns 9t..9t+7, stride-9 pad);
  // [2304,2560) packed states; [2560,2816) wnll; [2816,3072) fls; [3072,3328) cnt.
  __shared__ unsigned int lds[3328];
  unsigned int* chunkw = lds;
  unsigned int* stw = lds + 2304;
  float* wnw = (float*)(lds + 2560);
  float* flw = (float*)(lds + 2816);
  int*   cnw = (int*)(lds + 3072);

  const int tid = threadIdx.x;
  const int w = tid >> 6, lane = tid & 63;
  const int waveBase = blockIdx.x * E_BLOCK + w * E_WAVE;

  float wnll = 0.f, flraw = 0.f; int cnt1 = 0;

  if (waveBase + E_WAVE <= B) {
    // fast path: wave fully in range; software pipeline depth PF (all in VGPRs)
    const int e0 = waveBase + lane * 4;
    const float4* __restrict__ px = (const float4*)(x + 2 * (size_t)e0);
    const int4*   __restrict__ pt = (const int4*)(tgt + e0);

    float4 xa[PF + 1], xb[PF + 1]; int4 t4[PF + 1];
    #pragma unroll
    for (int p = 0; p < PF; ++p) {        // prime: 3*PF loads in flight
      xa[p] = px[p * 128]; xb[p] = px[p * 128 + 1]; t4[p] = pt[p * 64];
    }
    #pragma unroll
    for (int j = 0; j < QITERS; ++j) {
      const int s = j % (PF + 1);
      const int d = (j + PF) % (PF + 1);
      if (j + PF < QITERS) {              // keep 3*PF loads in flight during compute
        const int o = (j + PF) * 128;
        xa[d] = px[o]; xb[d] = px[o + 1]; t4[d] = pt[(j + PF) * 64];
      }
      unsigned int word = 0;
      elem_math(xa[s].x, xa[s].y, t4[s].x, 0, wnll, flraw, cnt1, word);
      elem_math(xa[s].z, xa[s].w, t4[s].y, 1, wnll, flraw, cnt1, word);
      elem_math(xb[s].x, xb[s].y, t4[s].z, 2, wnll, flraw, cnt1, word);
      elem_math(xb[s].z, xb[s].w, t4[s].w, 3, wnll, flraw, cnt1, word);
      const int qi = w * 512 + (j << 6) + lane;        // block-local quad index
      chunkw[(qi >> 3) * 9 + (qi & 7)] = word;
    }
  } else {
    // slow path: per-element guard (only the final partial block, if any)
    for (int j = 0; j < QITERS; ++j) {
      unsigned int word = 0;
      for (int k = 0; k < 4; ++k) {
        const int e = waveBase + ((j << 6) + lane) * 4 + k;
        if (e < B) {
          elem_math(x[2 * (size_t)e], x[2 * (size_t)e + 1], tgt[e], k,
                    wnll, flraw, cnt1, word);
        }
      }
      const int qi = w * 512 + (j << 6) + lane;
      chunkw[(qi >> 3) * 9 + (qi & 7)] = word;
    }
  }
  __syncthreads();

  // Phase 2: each thread serially chains its contiguous 32-element chunk.
  int s0 = 0, f0 = 0, l0 = 0, s1 = 0, f1 = 0, l1 = 0;
  #pragma unroll
  for (int r = 0; r < 8; ++r) {
    const unsigned int wv = chunkw[tid * 9 + r];
    #pragma unroll
    for (int k = 0; k < 4; ++k) {
      const unsigned int b = (wv >> (8 * k)) & 7u;
      if (b & 4u) {
        const int sv = (int)((b & 1u) << 1) - 1;
        const int t  = (int)((b >> 1) & 1u);
        const int lv = t ? l1 : l0;
        const int add = lv * sv;
        if (t) { s1 += add; l1 = sv; f1 = f1 ? f1 : sv; }
        else   { s0 += add; l0 = sv; f0 = f0 ? f0 : sv; }
      }
    }
  }
  stw[tid] = (unsigned)(s0 + 128) | ((unsigned)(f0 + 1) << 8) | ((unsigned)(l0 + 1) << 10)
           | ((unsigned)(s1 + 128) << 16) | ((unsigned)(f1 + 1) << 24) | ((unsigned)(l1 + 1) << 26);
  wnw[tid] = wnll; flw[tid] = flraw * -0.69314718f; cnw[tid] = cnt1;
  __syncthreads();

  if (w == 0) {
    int S0 = 0, F0 = 0, L0 = 0, S1 = 0, F1 = 0, L1 = 0;
    float W = 0.f, F = 0.f; int C = 0;
    #pragma unroll
    for (int q = 0; q < 4; ++q) {
      const int i = lane * 4 + q;                 // ascending element order
      const unsigned int pk = stw[i];
      comb0(S0, F0, L0, (int)(pk & 255u) - 128, (int)((pk >> 8) & 3u) - 1, (int)((pk >> 10) & 3u) - 1);
      comb0(S1, F1, L1, (int)((pk >> 16) & 255u) - 128, (int)((pk >> 24) & 3u) - 1, (int)((pk >> 26) & 3u) - 1);
      W += wnw[i]; F += flw[i]; C += cnw[i];
    }
    #pragma unroll
    for (int k = 0; k < 6; ++k) {
      const int m = 1 << k;
      bfly_step(m, lane, S0, F0, L0);
      bfly_step(m, lane, S1, F1, L1);
      W += __shfl_xor(W, m); F += __shfl_xor(F, m); C += __shfl_xor(C, m);
    }
    if (lane == 0) {
      BlockRec r;
      r.s0 = S0; r.p0 = (F0 + 1) | ((L0 + 1) << 4);
      r.s1 = S1; r.p1 = (F1 + 1) | ((L1 + 1) << 4);
      r.wnll = W; r.fl = F; r.cnt1 = C; r.pad = 0;
      recs[blockIdx.x] = r;
    }
  }
}

__global__ __launch_bounds__(256) void loss_pass2(
    const BlockRec* __restrict__ recs, int NB, int B, float* __restrict__ out) {
  __shared__ int sS0[256], sF0[256], sL0[256], sS1[256], sF1[256], sL1[256], sC[256];
  __shared__ double sW[256], sFl[256];
  const int tid = threadIdx.x, w = tid >> 6, lane = tid & 63;
  const int R = (NB + 255) >> 8;

  int s0 = 0, f0 = 0, l0 = 0, s1 = 0, f1 = 0, l1 = 0;
  double W = 0.0, Fd = 0.0; int C = 0;
  for (int r = 0; r < R; ++r) {
    const int b = tid * R + r;
    if (b < NB) {
      const BlockRec rec = recs[b];
      comb0(s0, f0, l0, rec.s0, (rec.p0 & 3) - 1, ((rec.p0 >> 4) & 3) - 1);
      comb0(s1, f1, l1, rec.s1, (rec.p1 & 3) - 1, ((rec.p1 >> 4) & 3) - 1);
      W += (double)rec.wnll; Fd += (double)rec.fl; C += rec.cnt1;
    }
  }
  sS0[tid] = s0; sF0[tid] = f0; sL0[tid] = l0;
  sS1[tid] = s1; sF1[tid] = f1; sL1[tid] = l1;
  sC[tid] = C; sW[tid] = W; sFl[tid] = Fd;
  __syncthreads();

  if (w == 0) {
    int S0 = 0, F0 = 0, L0 = 0, S1 = 0, F1 = 0, L1 = 0; int Ct = 0;
    double Wt = 0.0, Ft = 0.0;
    #pragma unroll
    for (int q = 0; q < 4; ++q) {
      const int i = lane * 4 + q;
      comb0(S0, F0, L0, sS0[i], sF0[i], sL0[i]);
      comb0(S1, F1, L1, sS1[i], sF1[i], sL1[i]);
      Wt += sW[i]; Ft += sFl[i]; Ct += sC[i];
    }
    #pragma unroll
    for (int k = 0; k < 6; ++k) {
      const int m = 1 << k;
      bfly_step(m, lane, S0, F0, L0);
      bfly_step(m, lane, S1, F1, L1);
      Wt += __shfl_xor(Wt, m); Ft += __shfl_xor(Ft, m); Ct += __shfl_xor(Ct, m);
    }
    if (lane == 0) {
      const double n1 = (double)Ct, n0 = (double)B - n1;
      const double sw = 0.15 * n0 + 0.85 * n1;
      const double ldam  = Wt / sw;
      const double focal = Ft / (double)B;
      const double q0 = (n0 > 0.0) ? (double)S0 / n0 : 0.0;
      const double q1 = (n1 > 0.0) ? (double)S1 / n1 : 0.0;
      const double dq = q0 - q1;
      out[0] = (float)(ldam + focal + dq * dq);
    }
  }
}

extern "C" void kernel_launch(void* const* d_in, const int* in_sizes, int n_in,
                              void* d_out, int out_size, void* d_ws, size_t ws_size,
                              hipStream_t stream) {
  const float* x  = (const float*)d_in[0];
  const int* tgt  = (const int*)d_in[1];
  float* out      = (float*)d_out;
  const int B  = in_sizes[1];                       // rows (16777216)
  const int NB = (B + E_BLOCK - 1) / E_BLOCK;       // 2048
  BlockRec* recs = (BlockRec*)d_ws;                 // 64 KB scratch
  loss_pass1<<<NB, 256, 0, stream>>>(x, tgt, recs, B);
  loss_pass2<<<1, 256, 0, stream>>>(recs, NB, B, out);
}

// Round 7
// 240.334 us; speedup vs baseline: 1.0284x; 1.0086x over previous
//
#include <hip/hip_runtime.h>

// B = 16777216 rows, 2 cols. 2048 blocks x 8192 elems, 32 elems/thread.
#define E_BLOCK 8192
#define E_WAVE  2048
#define QITERS  8              // per-thread iterations, 4 consecutive elems each

#define M1f     0.2771814156f  // 0.5*(85/900)^0.25  (class-1 LDAM margin)
#define C_A1    60.0f          // za = tf*60 - 30      -> +-30
#define C_C1    (30.0f*M1f - 15.0f) // zc = tf*C_C1 + 15

#define EXP2F(v) __builtin_amdgcn_exp2f(v)   // v_exp_f32: 2^x
#define LOG2F(v) __builtin_amdgcn_logf(v)    // v_log_f32: log2(x)

struct BlockRec {
  int s0, p0, s1, p1;   // chain sum + packed (f+1) | (l+1)<<4 per class
  float wnll, fl;
  int cnt1, pad;
};

// 0-encoded chain state: f==0 => empty. f,l in {-1,0,+1}. Ordered combine.
__device__ __forceinline__ void comb0(int &s, int &f, int &l, int sb, int fb, int lb) {
  s += sb + l * fb;
  f = f ? f : fb;
  l = fb ? lb : l;
}

__device__ __forceinline__ void bfly_step(int m, int lane, int &s, int &f, int &l) {
  const int os = __shfl_xor(s, m), of = __shfl_xor(f, m), ol = __shfl_xor(l, m);
  const bool up = (lane & m) != 0;
  int as = up ? os : s, af = up ? of : f, al = up ? ol : l;
  const int bs = up ? s : os, bf = up ? f : of, bl = up ? l : ol;
  comb0(as, af, al, bs, bf, bl);
  s = as; f = af; l = al;
}

__device__ __forceinline__ void elem_math(float x0, float x1, int t, int k,
                                          float &wnll, float &flraw, int &cnt1,
                                          unsigned int &word) {
  const float tf  = (float)t;
  const float wgt = fmaf(tf, 0.7f, 0.15f);          // 0.15 / 0.85
  const float d   = x0 - x1;
  const float za  = fmaf(tf, C_A1, -30.0f);
  const float zc  = fmaf(tf, C_C1, 15.0f);
  const float z   = fmaf(za, d, zc);                // 30*(t? d+M1 : 0.5-d)
  const float ex  = EXP2F(fabsf(z) * -1.44269504f);
  const float lp  = LOG2F(1.0f + ex);
  const float sp  = fmaf(0.69314718f, lp, fmaxf(z, 0.0f));  // softplus(z)
  wnll = fmaf(wgt, sp, wnll);
  const float om  = 1.0f - x1;
  const float q   = t ? x1 : om;
  const float r   = t ? om : x1;
  const float lg2 = LOG2F(q + 1e-9f);
  const float wr2 = (wgt * r) * r;
  flraw = fmaf(wr2, lg2, flraw);                    // * -ln2 applied at end
  cnt1 += t;
  const unsigned int code = 4u | (unsigned int)(d > 0.0f) | ((unsigned int)t << 1);
  word |= code << (8 * k);
}

__global__ __launch_bounds__(256, 2) void loss_pass1(
    const float* __restrict__ x, const int* __restrict__ tgt,
    BlockRec* __restrict__ recs, int B) {
  // LDS words: [0,2304) chunk words (thread t owns 9t..9t+7, stride-9 pad);
  // [2304,2560) packed states; [2560,2816) wnll; [2816,3072) fls; [3072,3328) cnt.
  __shared__ unsigned int lds[3328];
  unsigned int* chunkw = lds;
  unsigned int* stw = lds + 2304;
  float* wnw = (float*)(lds + 2560);
  float* flw = (float*)(lds + 2816);
  int*   cnw = (int*)(lds + 3072);

  const int tid = threadIdx.x;
  const int w = tid >> 6, lane = tid & 63;
  const int waveBase = blockIdx.x * E_BLOCK + w * E_WAVE;

  float wnll = 0.f, flraw = 0.f; int cnt1 = 0;

  if (waveBase + E_WAVE <= B) {
    // fast path: hoist ALL loads for the 32-element chunk (24 VMEM insts,
    // 384 B/thread) before any compute — maximal MLP, registers permitting.
    const int e0 = waveBase + lane * 4;
    const float4* __restrict__ px = (const float4*)(x + 2 * (size_t)e0);
    const int4*   __restrict__ pt = (const int4*)(tgt + e0);

    float4 xa[QITERS], xb[QITERS]; int4 t4[QITERS];
    #pragma unroll
    for (int j = 0; j < QITERS; ++j) {
      xa[j] = px[j * 128];
      xb[j] = px[j * 128 + 1];
      t4[j] = pt[j * 64];
    }
    #pragma unroll
    for (int j = 0; j < QITERS; ++j) {
      unsigned int word = 0;
      elem_math(xa[j].x, xa[j].y, t4[j].x, 0, wnll, flraw, cnt1, word);
      elem_math(xa[j].z, xa[j].w, t4[j].y, 1, wnll, flraw, cnt1, word);
      elem_math(xb[j].x, xb[j].y, t4[j].z, 2, wnll, flraw, cnt1, word);
      elem_math(xb[j].z, xb[j].w, t4[j].w, 3, wnll, flraw, cnt1, word);
      const int qi = w * 512 + (j << 6) + lane;        // block-local quad index
      chunkw[(qi >> 3) * 9 + (qi & 7)] = word;
    }
  } else {
    // slow path: per-element guard (only the final partial block, if any)
    for (int j = 0; j < QITERS; ++j) {
      unsigned int word = 0;
      for (int k = 0; k < 4; ++k) {
        const int e = waveBase + ((j << 6) + lane) * 4 + k;
        if (e < B) {
          elem_math(x[2 * (size_t)e], x[2 * (size_t)e + 1], tgt[e], k,
                    wnll, flraw, cnt1, word);
        }
      }
      const int qi = w * 512 + (j << 6) + lane;
      chunkw[(qi >> 3) * 9 + (qi & 7)] = word;
    }
  }
  __syncthreads();

  // Phase 2: each thread serially chains its contiguous 32-element chunk.
  int s0 = 0, f0 = 0, l0 = 0, s1 = 0, f1 = 0, l1 = 0;
  #pragma unroll
  for (int r = 0; r < 8; ++r) {
    const unsigned int wv = chunkw[tid * 9 + r];
    #pragma unroll
    for (int k = 0; k < 4; ++k) {
      const unsigned int b = (wv >> (8 * k)) & 7u;
      if (b & 4u) {
        const int sv = (int)((b & 1u) << 1) - 1;
        const int t  = (int)((b >> 1) & 1u);
        const int lv = t ? l1 : l0;
        const int add = lv * sv;
        if (t) { s1 += add; l1 = sv; f1 = f1 ? f1 : sv; }
        else   { s0 += add; l0 = sv; f0 = f0 ? f0 : sv; }
      }
    }
  }
  stw[tid] = (unsigned)(s0 + 128) | ((unsigned)(f0 + 1) << 8) | ((unsigned)(l0 + 1) << 10)
           | ((unsigned)(s1 + 128) << 16) | ((unsigned)(f1 + 1) << 24) | ((unsigned)(l1 + 1) << 26);
  wnw[tid] = wnll; flw[tid] = flraw * -0.69314718f; cnw[tid] = cnt1;
  __syncthreads();

  if (w == 0) {
    int S0 = 0, F0 = 0, L0 = 0, S1 = 0, F1 = 0, L1 = 0;
    float W = 0.f, F = 0.f; int C = 0;
    #pragma unroll
    for (int q = 0; q < 4; ++q) {
      const int i = lane * 4 + q;                 // ascending element order
      const unsigned int pk = stw[i];
      comb0(S0, F0, L0, (int)(pk & 255u) - 128, (int)((pk >> 8) & 3u) - 1, (int)((pk >> 10) & 3u) - 1);
      comb0(S1, F1, L1, (int)((pk >> 16) & 255u) - 128, (int)((pk >> 24) & 3u) - 1, (int)((pk >> 26) & 3u) - 1);
      W += wnw[i]; F += flw[i]; C += cnw[i];
    }
    #pragma unroll
    for (int k = 0; k < 6; ++k) {
      const int m = 1 << k;
      bfly_step(m, lane, S0, F0, L0);
      bfly_step(m, lane, S1, F1, L1);
      W += __shfl_xor(W, m); F += __shfl_xor(F, m); C += __shfl_xor(C, m);
    }
    if (lane == 0) {
      BlockRec r;
      r.s0 = S0; r.p0 = (F0 + 1) | ((L0 + 1) << 4);
      r.s1 = S1; r.p1 = (F1 + 1) | ((L1 + 1) << 4);
      r.wnll = W; r.fl = F; r.cnt1 = C; r.pad = 0;
      recs[blockIdx.x] = r;
    }
  }
}

__global__ __launch_bounds__(256) void loss_pass2(
    const BlockRec* __restrict__ recs, int NB, int B, float* __restrict__ out) {
  __shared__ int sS0[256], sF0[256], sL0[256], sS1[256], sF1[256], sL1[256], sC[256];
  __shared__ double sW[256], sFl[256];
  const int tid = threadIdx.x, w = tid >> 6, lane = tid & 63;
  const int R = (NB + 255) >> 8;

  int s0 = 0, f0 = 0, l0 = 0, s1 = 0, f1 = 0, l1 = 0;
  double W = 0.0, Fd = 0.0; int C = 0;
  for (int r = 0; r < R; ++r) {
    const int b = tid * R + r;
    if (b < NB) {
      const BlockRec rec = recs[b];
      comb0(s0, f0, l0, rec.s0, (rec.p0 & 3) - 1, ((rec.p0 >> 4) & 3) - 1);
      comb0(s1, f1, l1, rec.s1, (rec.p1 & 3) - 1, ((rec.p1 >> 4) & 3) - 1);
      W += (double)rec.wnll; Fd += (double)rec.fl; C += rec.cnt1;
    }
  }
  sS0[tid] = s0; sF0[tid] = f0; sL0[tid] = l0;
  sS1[tid] = s1; sF1[tid] = f1; sL1[tid] = l1;
  sC[tid] = C; sW[tid] = W; sFl[tid] = Fd;
  __syncthreads();

  if (w == 0) {
    int S0 = 0, F0 = 0, L0 = 0, S1 = 0, F1 = 0, L1 = 0; int Ct = 0;
    double Wt = 0.0, Ft = 0.0;
    #pragma unroll
    for (int q = 0; q < 4; ++q) {
      const int i = lane * 4 + q;
      comb0(S0, F0, L0, sS0[i], sF0[i], sL0[i]);
      comb0(S1, F1, L1, sS1[i], sF1[i], sL1[i]);
      Wt += sW[i]; Ft += sFl[i]; Ct += sC[i];
    }
    #pragma unroll
    for (int k = 0; k < 6; ++k) {
      const int m = 1 << k;
      bfly_step(m, lane, S0, F0, L0);
      bfly_step(m, lane, S1, F1, L1);
      Wt += __shfl_xor(Wt, m); Ft += __shfl_xor(Ft, m); Ct += __shfl_xor(Ct, m);
    }
    if (lane == 0) {
      const double n1 = (double)Ct, n0 = (double)B - n1;
      const double sw = 0.15 * n0 + 0.85 * n1;
      const double ldam  = Wt / sw;
      const double focal = Ft / (double)B;
      const double q0 = (n0 > 0.0) ? (double)S0 / n0 : 0.0;
      const double q1 = (n1 > 0.0) ? (double)S1 / n1 : 0.0;
      const double dq = q0 - q1;
      out[0] = (float)(ldam + focal + dq * dq);
    }
  }
}

extern "C" void kernel_launch(void* const* d_in, const int* in_sizes, int n_in,
                              void* d_out, int out_size, void* d_ws, size_t ws_size,
                              hipStream_t stream) {
  const float* x  = (const float*)d_in[0];
  const int* tgt  = (const int*)d_in[1];
  float* out      = (float*)d_out;
  const int B  = in_sizes[1];                       // rows (16777216)
  const int NB = (B + E_BLOCK - 1) / E_BLOCK;       // 2048
  BlockRec* recs = (BlockRec*)d_ws;                 // 64 KB scratch
  loss_pass1<<<NB, 256, 0, stream>>>(x, tgt, recs, B);
  loss_pass2<<<1, 256, 0, stream>>>(recs, NB, B, out);
}